// Round 1
// baseline (382.286 us; speedup 1.0000x reference)
//
#include <hip/hip_runtime.h>
#include <math.h>

#define N_TOK 40000
#define D_MODEL 256
#define NHEAD 8
#define NPOINT 8
#define DHEAD 32
#define HW_DIM 200

// ---------------------------------------------------------------------------
// Generic tiled fp32 GEMM: C[M x Nout] = A[M x K] @ B[K x Nout] + bias
// BM=BN=64, BK=16, 256 threads, 4x4 microtile per thread.
// SCATTER=true writes head-major: C[(col>>5)][row][col&31]  (for value proj)
// Requires M%64==0, Nout%64==0, K%16==0 (true for all our shapes).
// ---------------------------------------------------------------------------
template<bool SCATTER>
__global__ __launch_bounds__(256)
void gemm_f32(const float* __restrict__ A, const float* __restrict__ B,
              const float* __restrict__ bias, float* __restrict__ C,
              int M, int Nout, int K)
{
    const int BM = 64, BN = 64, BK = 16;
    __shared__ float As[BK][BM + 4];   // +4 pad keeps 16B alignment, breaks bank stride
    __shared__ float Bs[BK][BN];

    const int tid = threadIdx.x;
    const int tx  = tid & 15;          // col group 0..15
    const int ty  = tid >> 4;          // row group 0..15
    const int m0  = blockIdx.y * BM;
    const int n0  = blockIdx.x * BN;

    // A staging map: each thread loads float4 along K
    const int am = tid >> 2;           // 0..63 row within tile
    const int ak = (tid & 3) << 2;     // 0,4,8,12
    // B staging map: each thread loads float4 along N
    const int bk = tid >> 4;           // 0..15
    const int bn = (tid & 15) << 2;    // 0..60

    float acc[4][4] = {};

    for (int k0 = 0; k0 < K; k0 += BK) {
        float4 a = *(const float4*)(A + (size_t)(m0 + am) * K + k0 + ak);
        float4 b = *(const float4*)(B + (size_t)(k0 + bk) * Nout + n0 + bn);
        __syncthreads();               // previous iter's LDS reads complete
        As[ak + 0][am] = a.x;
        As[ak + 1][am] = a.y;
        As[ak + 2][am] = a.z;
        As[ak + 3][am] = a.w;
        *(float4*)&Bs[bk][bn] = b;
        __syncthreads();

        #pragma unroll
        for (int k = 0; k < BK; k++) {
            float4 av = *(const float4*)&As[k][ty << 2];
            float4 bv = *(const float4*)&Bs[k][tx << 2];
            float ar[4] = {av.x, av.y, av.z, av.w};
            float br[4] = {bv.x, bv.y, bv.z, bv.w};
            #pragma unroll
            for (int i = 0; i < 4; i++)
                #pragma unroll
                for (int j = 0; j < 4; j++)
                    acc[i][j] = fmaf(ar[i], br[j], acc[i][j]);
        }
    }

    float4 bb = *(const float4*)(bias + n0 + (tx << 2));
    float br[4] = {bb.x, bb.y, bb.z, bb.w};
    const int col = n0 + (tx << 2);
    #pragma unroll
    for (int i = 0; i < 4; i++) {
        const int row = m0 + (ty << 2) + i;
        float4 o;
        o.x = acc[i][0] + br[0];
        o.y = acc[i][1] + br[1];
        o.z = acc[i][2] + br[2];
        o.w = acc[i][3] + br[3];
        if (SCATTER) {
            const int h = col >> 5;
            const int c = col & 31;
            *(float4*)(C + (size_t)h * M * 32 + (size_t)row * 32 + c) = o;
        } else {
            *(float4*)(C + (size_t)row * Nout + col) = o;
        }
    }
}

// ---------------------------------------------------------------------------
// Sampling: per (token n, head h): softmax over 8 logits, 8 bilinear samples
// from vh[h][y*200+x][d], weighted-sum into mid[n][h*32+d].
// Block = 256 threads = 8 heads x 32 channels; grid = N_TOK (n = blockIdx.x).
// ---------------------------------------------------------------------------
__global__ __launch_bounds__(256)
void sample_k(const float* __restrict__ vh,      // [8][40000][32]
              const float* __restrict__ offs,    // [N][128]
              const float* __restrict__ logits,  // [N][64]
              const float* __restrict__ refp,    // [N][2]
              float* __restrict__ mid)           // [N][256]
{
    const int h = threadIdx.x >> 5;   // 0..7
    const int d = threadIdx.x & 31;   // 0..31
    const int n = blockIdx.x;

    const float rx = refp[2 * n + 0];
    const float ry = refp[2 * n + 1];

    const float* lg = logits + (size_t)n * 64 + h * 8;
    float l[NPOINT];
    float m = -1e30f;
    #pragma unroll
    for (int p = 0; p < NPOINT; p++) { l[p] = lg[p]; m = fmaxf(m, l[p]); }
    float s = 0.f;
    #pragma unroll
    for (int p = 0; p < NPOINT; p++) { l[p] = expf(l[p] - m); s += l[p]; }
    const float inv = 1.0f / s;

    const float* ofs = offs + (size_t)n * 128 + h * 16;
    const float* vb  = vh + (size_t)h * N_TOK * DHEAD + d;

    float acc = 0.f;
    #pragma unroll
    for (int p = 0; p < NPOINT; p++) {
        float lx = rx + ofs[2 * p + 0] * (1.0f / (float)HW_DIM);
        float ly = ry + ofs[2 * p + 1] * (1.0f / (float)HW_DIM);
        lx = fminf(fmaxf(lx, 0.f), 1.f);
        ly = fminf(fmaxf(ly, 0.f), 1.f);
        const float x = lx * (float)HW_DIM - 0.5f;
        const float y = ly * (float)HW_DIM - 0.5f;
        const float x0f = floorf(x), y0f = floorf(y);
        const float wx = x - x0f, wy = y - y0f;
        const int x0 = (int)x0f, y0 = (int)y0f;
        const int x1 = x0 + 1,   y1 = y0 + 1;
        const bool vx0 = (x0 >= 0) & (x0 < HW_DIM);
        const bool vx1 = (x1 >= 0) & (x1 < HW_DIM);
        const bool vy0 = (y0 >= 0) & (y0 < HW_DIM);
        const bool vy1 = (y1 >= 0) & (y1 < HW_DIM);
        float v00 = 0.f, v01 = 0.f, v10 = 0.f, v11 = 0.f;
        if (vy0 & vx0) v00 = vb[(size_t)(y0 * HW_DIM + x0) * DHEAD];
        if (vy0 & vx1) v01 = vb[(size_t)(y0 * HW_DIM + x1) * DHEAD];
        if (vy1 & vx0) v10 = vb[(size_t)(y1 * HW_DIM + x0) * DHEAD];
        if (vy1 & vx1) v11 = vb[(size_t)(y1 * HW_DIM + x1) * DHEAD];
        const float sv = (1.f - wx) * (1.f - wy) * v00
                       + wx * (1.f - wy) * v01
                       + (1.f - wx) * wy * v10
                       + wx * wy * v11;
        acc = fmaf(l[p] * inv, sv, acc);
    }
    mid[(size_t)n * D_MODEL + h * DHEAD + d] = acc;
}

// ---------------------------------------------------------------------------
extern "C" void kernel_launch(void* const* d_in, const int* in_sizes, int n_in,
                              void* d_out, int out_size, void* d_ws, size_t ws_size,
                              hipStream_t stream)
{
    const float* query  = (const float*)d_in[0];
    const float* value  = (const float*)d_in[1];
    const float* refp   = (const float*)d_in[2];
    const float* W_off  = (const float*)d_in[3];
    const float* b_off  = (const float*)d_in[4];
    const float* W_attn = (const float*)d_in[5];
    const float* b_attn = (const float*)d_in[6];
    const float* W_val  = (const float*)d_in[7];
    const float* b_val  = (const float*)d_in[8];
    const float* W_out  = (const float*)d_in[9];
    const float* b_out  = (const float*)d_in[10];
    float* out = (float*)d_out;

    // workspace layout (floats): offs | logits | vh | mid  = 112.6 MB total
    float* ws     = (float*)d_ws;
    float* offs   = ws;                                  // N*128
    float* logits = offs   + (size_t)N_TOK * 128;        // N*64
    float* vh     = logits + (size_t)N_TOK * 64;         // 8*N*32 = N*256
    float* mid    = vh     + (size_t)N_TOK * 256;        // N*256

    const dim3 blk(256);
    // offsets = query @ W_off + b_off          (40000 x 256 x 128)
    gemm_f32<false><<<dim3(2, 625), blk, 0, stream>>>(query, W_off, b_off, offs,
                                                      N_TOK, 128, 256);
    // attn logits = query @ W_attn + b_attn    (40000 x 256 x 64)
    gemm_f32<false><<<dim3(1, 625), blk, 0, stream>>>(query, W_attn, b_attn, logits,
                                                      N_TOK, 64, 256);
    // vh = head-major (value @ W_val + b_val)  (40000 x 256 x 256, scattered)
    gemm_f32<true><<<dim3(4, 625), blk, 0, stream>>>(value, W_val, b_val, vh,
                                                     N_TOK, 256, 256);
    // bilinear sampling + softmax-weighted sum -> mid
    sample_k<<<dim3(N_TOK), blk, 0, stream>>>(vh, offs, logits, refp, mid);
    // out = mid @ W_out + b_out                (40000 x 256 x 256)
    gemm_f32<false><<<dim3(4, 625), blk, 0, stream>>>(mid, W_out, b_out, out,
                                                      N_TOK, 256, 256);
}

// Round 2
// 315.608 us; speedup vs baseline: 1.2113x; 1.2113x over previous
//
#include <hip/hip_runtime.h>
#include <math.h>

#define N_TOK 40000
#define D_MODEL 256
#define NHEAD 8
#define NPOINT 8
#define DHEAD 32
#define HW_DIM 200

// ---------------------------------------------------------------------------
// Generic tiled fp32 GEMM: C[M x Nout] = A[M x K] @ B[K x Nout] + bias
// BM=BN=64, BK=16, 256 threads, 4x4 microtile per thread.
// SCATTER=true writes head-major: C[(col>>5)][row][col&31]  (for value proj)
// ---------------------------------------------------------------------------
template<bool SCATTER>
__global__ __launch_bounds__(256)
void gemm_f32(const float* __restrict__ A, const float* __restrict__ B,
              const float* __restrict__ bias, float* __restrict__ C,
              int M, int Nout, int K)
{
    const int BM = 64, BN = 64, BK = 16;
    __shared__ float As[BK][BM + 4];
    __shared__ float Bs[BK][BN];

    const int tid = threadIdx.x;
    const int tx  = tid & 15;
    const int ty  = tid >> 4;
    const int m0  = blockIdx.y * BM;
    const int n0  = blockIdx.x * BN;

    const int am = tid >> 2;
    const int ak = (tid & 3) << 2;
    const int bk = tid >> 4;
    const int bn = (tid & 15) << 2;

    float acc[4][4] = {};

    for (int k0 = 0; k0 < K; k0 += BK) {
        float4 a = *(const float4*)(A + (size_t)(m0 + am) * K + k0 + ak);
        float4 b = *(const float4*)(B + (size_t)(k0 + bk) * Nout + n0 + bn);
        __syncthreads();
        As[ak + 0][am] = a.x;
        As[ak + 1][am] = a.y;
        As[ak + 2][am] = a.z;
        As[ak + 3][am] = a.w;
        *(float4*)&Bs[bk][bn] = b;
        __syncthreads();

        #pragma unroll
        for (int k = 0; k < BK; k++) {
            float4 av = *(const float4*)&As[k][ty << 2];
            float4 bv = *(const float4*)&Bs[k][tx << 2];
            float ar[4] = {av.x, av.y, av.z, av.w};
            float br[4] = {bv.x, bv.y, bv.z, bv.w};
            #pragma unroll
            for (int i = 0; i < 4; i++)
                #pragma unroll
                for (int j = 0; j < 4; j++)
                    acc[i][j] = fmaf(ar[i], br[j], acc[i][j]);
        }
    }

    float4 bb = *(const float4*)(bias + n0 + (tx << 2));
    float br[4] = {bb.x, bb.y, bb.z, bb.w};
    const int col = n0 + (tx << 2);
    #pragma unroll
    for (int i = 0; i < 4; i++) {
        const int row = m0 + (ty << 2) + i;
        float4 o;
        o.x = acc[i][0] + br[0];
        o.y = acc[i][1] + br[1];
        o.z = acc[i][2] + br[2];
        o.w = acc[i][3] + br[3];
        if (SCATTER) {
            const int h = col >> 5;
            const int c = col & 31;
            *(float4*)(C + (size_t)h * M * 32 + (size_t)row * 32 + c) = o;
        } else {
            *(float4*)(C + (size_t)row * Nout + col) = o;
        }
    }
}

// ---------------------------------------------------------------------------
// Sampling v2: one wave per token. Lane = (h, j), h = lane>>3, j = lane&7.
// Phase 1: lane (h, p=j) computes softmax weight + 4 corner indices +
//          4 combined bilinear weights for point p; stores to LDS.
// Phase 2: lane (h, j) accumulates channel quad j (float4) over 8 points x
//          4 corners, reading per-point data from LDS (broadcast).
// Block = 256 threads = 4 waves = 4 tokens; grid = N_TOK/4.
// ---------------------------------------------------------------------------
__global__ __launch_bounds__(256)
void sample_k(const float* __restrict__ vh,      // [8][40000][32]
              const float* __restrict__ offs,    // [N][128]
              const float* __restrict__ logits,  // [N][64]
              const float* __restrict__ refp,    // [N][2]
              float* __restrict__ mid)           // [N][256]
{
    __shared__ int4   s_idx[4][64];   // [wave][p*8+h]
    __shared__ float4 s_w[4][64];

    const int wave = threadIdx.x >> 6;
    const int lane = threadIdx.x & 63;
    const int n    = blockIdx.x * 4 + wave;
    const int h    = lane >> 3;
    const int j    = lane & 7;

    const float rx = refp[2 * n + 0];
    const float ry = refp[2 * n + 1];

    // ---- phase 1: point p = j for head h ----
    {
        const float l = logits[(size_t)n * 64 + h * 8 + j];
        float m = l;
        m = fmaxf(m, __shfl_xor(m, 1));
        m = fmaxf(m, __shfl_xor(m, 2));
        m = fmaxf(m, __shfl_xor(m, 4));
        const float e = expf(l - m);
        float s = e;
        s += __shfl_xor(s, 1);
        s += __shfl_xor(s, 2);
        s += __shfl_xor(s, 4);
        const float aw = e * (1.0f / s);

        const float2 o = *(const float2*)(offs + (size_t)n * 128 + h * 16 + j * 2);
        float lx = rx + o.x * (1.0f / (float)HW_DIM);
        float ly = ry + o.y * (1.0f / (float)HW_DIM);
        lx = fminf(fmaxf(lx, 0.f), 1.f);
        ly = fminf(fmaxf(ly, 0.f), 1.f);
        const float x = lx * (float)HW_DIM - 0.5f;
        const float y = ly * (float)HW_DIM - 0.5f;
        const float x0f = floorf(x), y0f = floorf(y);
        const float wx = x - x0f, wy = y - y0f;
        const int x0 = (int)x0f, y0 = (int)y0f;
        const int x1 = x0 + 1,   y1 = y0 + 1;
        const float vx0 = (x0 >= 0 && x0 < HW_DIM) ? 1.f : 0.f;
        const float vx1 = (x1 >= 0 && x1 < HW_DIM) ? 1.f : 0.f;
        const float vy0 = (y0 >= 0 && y0 < HW_DIM) ? 1.f : 0.f;
        const float vy1 = (y1 >= 0 && y1 < HW_DIM) ? 1.f : 0.f;
        const int xc0 = min(max(x0, 0), HW_DIM - 1);
        const int xc1 = min(max(x1, 0), HW_DIM - 1);
        const int yc0 = min(max(y0, 0), HW_DIM - 1);
        const int yc1 = min(max(y1, 0), HW_DIM - 1);

        int4 ic;
        ic.x = yc0 * HW_DIM + xc0;
        ic.y = yc0 * HW_DIM + xc1;
        ic.z = yc1 * HW_DIM + xc0;
        ic.w = yc1 * HW_DIM + xc1;
        float4 wc;
        wc.x = (1.f - wx) * (1.f - wy) * aw * vy0 * vx0;
        wc.y = wx * (1.f - wy) * aw * vy0 * vx1;
        wc.z = (1.f - wx) * wy * aw * vy1 * vx0;
        wc.w = wx * wy * aw * vy1 * vx1;

        s_idx[wave][j * 8 + h] = ic;
        s_w[wave][j * 8 + h]   = wc;
    }
    __syncthreads();

    // ---- phase 2: channel quad j of head h ----
    const char* vb = (const char*)vh;
    // byte offset of (head h, token idx, channel j*4): (h*40000 + idx)*128 + j*16
    const unsigned int hj = (unsigned int)h * (N_TOK * 128u) + (unsigned int)j * 16u;

    float4 acc = {0.f, 0.f, 0.f, 0.f};
    #pragma unroll
    for (int p = 0; p < NPOINT; p++) {
        const int4   ic = s_idx[wave][p * 8 + h];
        const float4 wc = s_w[wave][p * 8 + h];
        const float4 v0 = *(const float4*)(vb + (hj + ((unsigned int)ic.x << 7)));
        const float4 v1 = *(const float4*)(vb + (hj + ((unsigned int)ic.y << 7)));
        const float4 v2 = *(const float4*)(vb + (hj + ((unsigned int)ic.z << 7)));
        const float4 v3 = *(const float4*)(vb + (hj + ((unsigned int)ic.w << 7)));
        acc.x = fmaf(wc.x, v0.x, acc.x); acc.y = fmaf(wc.x, v0.y, acc.y);
        acc.z = fmaf(wc.x, v0.z, acc.z); acc.w = fmaf(wc.x, v0.w, acc.w);
        acc.x = fmaf(wc.y, v1.x, acc.x); acc.y = fmaf(wc.y, v1.y, acc.y);
        acc.z = fmaf(wc.y, v1.z, acc.z); acc.w = fmaf(wc.y, v1.w, acc.w);
        acc.x = fmaf(wc.z, v2.x, acc.x); acc.y = fmaf(wc.z, v2.y, acc.y);
        acc.z = fmaf(wc.z, v2.z, acc.z); acc.w = fmaf(wc.z, v2.w, acc.w);
        acc.x = fmaf(wc.w, v3.x, acc.x); acc.y = fmaf(wc.w, v3.y, acc.y);
        acc.z = fmaf(wc.w, v3.z, acc.z); acc.w = fmaf(wc.w, v3.w, acc.w);
    }
    *(float4*)(mid + (size_t)n * D_MODEL + h * DHEAD + j * 4) = acc;
}

// ---------------------------------------------------------------------------
extern "C" void kernel_launch(void* const* d_in, const int* in_sizes, int n_in,
                              void* d_out, int out_size, void* d_ws, size_t ws_size,
                              hipStream_t stream)
{
    const float* query  = (const float*)d_in[0];
    const float* value  = (const float*)d_in[1];
    const float* refp   = (const float*)d_in[2];
    const float* W_off  = (const float*)d_in[3];
    const float* b_off  = (const float*)d_in[4];
    const float* W_attn = (const float*)d_in[5];
    const float* b_attn = (const float*)d_in[6];
    const float* W_val  = (const float*)d_in[7];
    const float* b_val  = (const float*)d_in[8];
    const float* W_out  = (const float*)d_in[9];
    const float* b_out  = (const float*)d_in[10];
    float* out = (float*)d_out;

    float* ws     = (float*)d_ws;
    float* offs   = ws;                                  // N*128
    float* logits = offs   + (size_t)N_TOK * 128;        // N*64
    float* vh     = logits + (size_t)N_TOK * 64;         // 8*N*32 = N*256
    float* mid    = vh     + (size_t)N_TOK * 256;        // N*256

    const dim3 blk(256);
    gemm_f32<false><<<dim3(2, 625), blk, 0, stream>>>(query, W_off, b_off, offs,
                                                      N_TOK, 128, 256);
    gemm_f32<false><<<dim3(1, 625), blk, 0, stream>>>(query, W_attn, b_attn, logits,
                                                      N_TOK, 64, 256);
    gemm_f32<true><<<dim3(4, 625), blk, 0, stream>>>(value, W_val, b_val, vh,
                                                     N_TOK, 256, 256);
    sample_k<<<dim3(N_TOK / 4), blk, 0, stream>>>(vh, offs, logits, refp, mid);
    gemm_f32<false><<<dim3(4, 625), blk, 0, stream>>>(mid, W_out, b_out, out,
                                                      N_TOK, 256, 256);
}

// Round 3
// 154.473 us; speedup vs baseline: 2.4748x; 2.0431x over previous
//
#include <hip/hip_runtime.h>
#include <math.h>

#define N_TOK 40000
#define D_MODEL 256
#define NHEAD 8
#define NPOINT 8
#define DHEAD 32
#define HW_DIM 200

typedef __attribute__((ext_vector_type(8))) short short8;
typedef __attribute__((ext_vector_type(4))) float f32x4;
typedef __attribute__((ext_vector_type(8))) unsigned short ushort8v;

__device__ inline unsigned short f2bf(float f) {
    union { float f; unsigned int u; } v; v.f = f;
    unsigned int r = v.u + 0x7FFFu + ((v.u >> 16) & 1u);   // RNE
    return (unsigned short)(r >> 16);
}

__device__ inline float4 bf4f(ushort4 u) {
    float4 r;
    r.x = __uint_as_float((unsigned)u.x << 16);
    r.y = __uint_as_float((unsigned)u.y << 16);
    r.z = __uint_as_float((unsigned)u.z << 16);
    r.w = __uint_as_float((unsigned)u.w << 16);
    return r;
}

// ---------------------------------------------------------------------------
// cast query+value fp32 -> bf16, vectorized 8/thread
// ---------------------------------------------------------------------------
__global__ __launch_bounds__(256)
void cast_qv(const float* __restrict__ q, const float* __restrict__ v,
             unsigned short* __restrict__ qb, unsigned short* __restrict__ vb)
{
    const int PER = (N_TOK * D_MODEL) / 8;          // 1,280,000
    int i = blockIdx.x * 256 + threadIdx.x;
    const float* s; unsigned short* d;
    if (i < PER) { s = q; d = qb; }
    else         { s = v; d = vb; i -= PER; }
    const float4* sp = (const float4*)s;
    float4 x = sp[(size_t)i * 2], y = sp[(size_t)i * 2 + 1];
    ushort8v o;
    o[0] = f2bf(x.x); o[1] = f2bf(x.y); o[2] = f2bf(x.z); o[3] = f2bf(x.w);
    o[4] = f2bf(y.x); o[5] = f2bf(y.y); o[6] = f2bf(y.z); o[7] = f2bf(y.w);
    *(ushort8v*)(d + (size_t)i * 8) = o;
}

// ---------------------------------------------------------------------------
// weight transpose + cast: WT[n][k] = bf16(W[k][n]), K=256 always
// blockIdx.y selects which weight; blockIdx.x = n; threadIdx.x = k
// ---------------------------------------------------------------------------
__global__ __launch_bounds__(256)
void wt_cast(const float* __restrict__ W0, const float* __restrict__ W1,
             const float* __restrict__ W2, const float* __restrict__ W3,
             unsigned short* __restrict__ T0, unsigned short* __restrict__ T1,
             unsigned short* __restrict__ T2, unsigned short* __restrict__ T3)
{
    const int which = blockIdx.y;
    const float* W; unsigned short* T; int N;
    if      (which == 0) { W = W0; T = T0; N = 128; }
    else if (which == 1) { W = W1; T = T1; N = 64;  }
    else if (which == 2) { W = W2; T = T2; N = 256; }
    else                 { W = W3; T = T3; N = 256; }
    const int n = blockIdx.x;
    if (n >= N) return;
    const int k = threadIdx.x;
    T[(size_t)n * 256 + k] = f2bf(W[(size_t)k * N + n]);
}

// ---------------------------------------------------------------------------
// bf16 MFMA GEMM: C[M x Nout] = A[M x 256] @ BT[Nout x 256]^T + bias
// 64x64 tile, 256 thr / 4 waves, each wave a 32x32 quadrant (2x2 frags of
// 16x16x32). global_load_lds width-16 staging, XOR k-chunk swizzle
// (kc' = kc ^ ((row>>1)&3)) applied to BOTH the global source and the
// ds_read (both-sides rule). SCATTER: C bf16 head-major vh[h][row][c].
// ---------------------------------------------------------------------------
template<bool SCATTER>
__global__ __launch_bounds__(256)
void gemm_bf16(const unsigned short* __restrict__ A,
               const unsigned short* __restrict__ BT,
               const float* __restrict__ bias,
               void* __restrict__ Cp, int M, int Nout)
{
    __shared__ short As[64 * 32];
    __shared__ short Bs[64 * 32];

    const int tid  = threadIdx.x;
    const int wid  = tid >> 6;
    const int lane = tid & 63;
    const int m0   = blockIdx.y * 64;
    const int n0   = blockIdx.x * 64;

    // staging map: slot s = tid -> (row = s>>2, kc = s&3), swizzled source
    const int srow  = tid >> 2;
    const int skc   = tid & 3;
    const int skc_s = skc ^ ((srow >> 1) & 3);
    const unsigned short* gA = A  + (size_t)(m0 + srow) * 256 + skc_s * 8;
    const unsigned short* gB = BT + (size_t)(n0 + srow) * 256 + skc_s * 8;
    auto* ldsA = (__attribute__((address_space(3))) char*)As + wid * 1024;
    auto* ldsB = (__attribute__((address_space(3))) char*)Bs + wid * 1024;

    const int r16 = lane & 15;
    const int g   = lane >> 4;          // desired global k-chunk

    f32x4 acc[2][2] = {};

    for (int k0 = 0; k0 < 256; k0 += 32) {
        __syncthreads();
        __builtin_amdgcn_global_load_lds(
            (const __attribute__((address_space(1))) void*)(gA + k0),
            (__attribute__((address_space(3))) void*)ldsA, 16, 0, 0);
        __builtin_amdgcn_global_load_lds(
            (const __attribute__((address_space(1))) void*)(gB + k0),
            (__attribute__((address_space(3))) void*)ldsB, 16, 0, 0);
        __syncthreads();   // compiler drains vmcnt before s_barrier

        short8 a[2], b[2];
        #pragma unroll
        for (int i = 0; i < 2; i++) {
            const int row = (wid >> 1) * 32 + i * 16 + r16;
            const int kra = g ^ ((row >> 1) & 3);
            a[i] = *(const short8*)(As + row * 32 + kra * 8);
            const int col = (wid & 1) * 32 + i * 16 + r16;
            const int krb = g ^ ((col >> 1) & 3);
            b[i] = *(const short8*)(Bs + col * 32 + krb * 8);
        }
        #pragma unroll
        for (int i = 0; i < 2; i++)
            #pragma unroll
            for (int j = 0; j < 2; j++)
                acc[i][j] = __builtin_amdgcn_mfma_f32_16x16x32_bf16(
                    a[i], b[j], acc[i][j], 0, 0, 0);
    }

    const int wr = (wid >> 1) * 32, wc = (wid & 1) * 32;
    #pragma unroll
    for (int j = 0; j < 2; j++) {
        const int col = n0 + wc + j * 16 + r16;
        const float bv = bias[col];
        #pragma unroll
        for (int i = 0; i < 2; i++) {
            #pragma unroll
            for (int r = 0; r < 4; r++) {
                const int row = m0 + wr + i * 16 + g * 4 + r;
                const float o = acc[i][j][r] + bv;
                if (SCATTER) {
                    const int h = col >> 5, c = col & 31;
                    ((unsigned short*)Cp)[(size_t)h * M * 32 + (size_t)row * 32 + c] = f2bf(o);
                } else {
                    ((float*)Cp)[(size_t)row * Nout + col] = o;
                }
            }
        }
    }
}

// ---------------------------------------------------------------------------
// Sampling: one wave per token; vh bf16; mid written bf16.
// ---------------------------------------------------------------------------
__global__ __launch_bounds__(256)
void sample_k(const unsigned short* __restrict__ vh,  // [8][40000][32] bf16
              const float* __restrict__ offs,         // [N][128]
              const float* __restrict__ logits,       // [N][64]
              const float* __restrict__ refp,         // [N][2]
              unsigned short* __restrict__ mid)       // [N][256] bf16
{
    __shared__ int4   s_idx[4][64];
    __shared__ float4 s_w[4][64];

    const int wave = threadIdx.x >> 6;
    const int lane = threadIdx.x & 63;
    const int n    = blockIdx.x * 4 + wave;
    const int h    = lane >> 3;
    const int j    = lane & 7;

    const float rx = refp[2 * n + 0];
    const float ry = refp[2 * n + 1];

    // ---- phase 1: point p = j for head h ----
    {
        const float l = logits[(size_t)n * 64 + h * 8 + j];
        float m = l;
        m = fmaxf(m, __shfl_xor(m, 1));
        m = fmaxf(m, __shfl_xor(m, 2));
        m = fmaxf(m, __shfl_xor(m, 4));
        const float e = expf(l - m);
        float s = e;
        s += __shfl_xor(s, 1);
        s += __shfl_xor(s, 2);
        s += __shfl_xor(s, 4);
        const float aw = e * (1.0f / s);

        const float2 o = *(const float2*)(offs + (size_t)n * 128 + h * 16 + j * 2);
        float lx = rx + o.x * (1.0f / (float)HW_DIM);
        float ly = ry + o.y * (1.0f / (float)HW_DIM);
        lx = fminf(fmaxf(lx, 0.f), 1.f);
        ly = fminf(fmaxf(ly, 0.f), 1.f);
        const float x = lx * (float)HW_DIM - 0.5f;
        const float y = ly * (float)HW_DIM - 0.5f;
        const float x0f = floorf(x), y0f = floorf(y);
        const float wx = x - x0f, wy = y - y0f;
        const int x0 = (int)x0f, y0 = (int)y0f;
        const int x1 = x0 + 1,   y1 = y0 + 1;
        const float vx0 = (x0 >= 0 && x0 < HW_DIM) ? 1.f : 0.f;
        const float vx1 = (x1 >= 0 && x1 < HW_DIM) ? 1.f : 0.f;
        const float vy0 = (y0 >= 0 && y0 < HW_DIM) ? 1.f : 0.f;
        const float vy1 = (y1 >= 0 && y1 < HW_DIM) ? 1.f : 0.f;
        const int xc0 = min(max(x0, 0), HW_DIM - 1);
        const int xc1 = min(max(x1, 0), HW_DIM - 1);
        const int yc0 = min(max(y0, 0), HW_DIM - 1);
        const int yc1 = min(max(y1, 0), HW_DIM - 1);

        int4 ic;
        ic.x = yc0 * HW_DIM + xc0;
        ic.y = yc0 * HW_DIM + xc1;
        ic.z = yc1 * HW_DIM + xc0;
        ic.w = yc1 * HW_DIM + xc1;
        float4 wc;
        wc.x = (1.f - wx) * (1.f - wy) * aw * vy0 * vx0;
        wc.y = wx * (1.f - wy) * aw * vy0 * vx1;
        wc.z = (1.f - wx) * wy * aw * vy1 * vx0;
        wc.w = wx * wy * aw * vy1 * vx1;

        s_idx[wave][j * 8 + h] = ic;
        s_w[wave][j * 8 + h]   = wc;
    }
    __syncthreads();

    // ---- phase 2: channel quad j of head h ----
    const char* vb = (const char*)vh;
    // byte offset of (head h, token idx, channel j*4): (h*40000 + idx)*64 + j*8
    const unsigned int hj = (unsigned int)h * (N_TOK * 64u) + (unsigned int)j * 8u;

    float4 acc = {0.f, 0.f, 0.f, 0.f};
    #pragma unroll
    for (int p = 0; p < NPOINT; p++) {
        const int4   ic = s_idx[wave][p * 8 + h];
        const float4 wc = s_w[wave][p * 8 + h];
        const float4 v0 = bf4f(*(const ushort4*)(vb + (hj + ((unsigned int)ic.x << 6))));
        const float4 v1 = bf4f(*(const ushort4*)(vb + (hj + ((unsigned int)ic.y << 6))));
        const float4 v2 = bf4f(*(const ushort4*)(vb + (hj + ((unsigned int)ic.z << 6))));
        const float4 v3 = bf4f(*(const ushort4*)(vb + (hj + ((unsigned int)ic.w << 6))));
        acc.x = fmaf(wc.x, v0.x, acc.x); acc.y = fmaf(wc.x, v0.y, acc.y);
        acc.z = fmaf(wc.x, v0.z, acc.z); acc.w = fmaf(wc.x, v0.w, acc.w);
        acc.x = fmaf(wc.y, v1.x, acc.x); acc.y = fmaf(wc.y, v1.y, acc.y);
        acc.z = fmaf(wc.y, v1.z, acc.z); acc.w = fmaf(wc.y, v1.w, acc.w);
        acc.x = fmaf(wc.z, v2.x, acc.x); acc.y = fmaf(wc.z, v2.y, acc.y);
        acc.z = fmaf(wc.z, v2.z, acc.z); acc.w = fmaf(wc.z, v2.w, acc.w);
        acc.x = fmaf(wc.w, v3.x, acc.x); acc.y = fmaf(wc.w, v3.y, acc.y);
        acc.z = fmaf(wc.w, v3.z, acc.z); acc.w = fmaf(wc.w, v3.w, acc.w);
    }
    ushort4 o;
    o.x = f2bf(acc.x); o.y = f2bf(acc.y); o.z = f2bf(acc.z); o.w = f2bf(acc.w);
    *(ushort4*)(mid + (size_t)n * D_MODEL + h * DHEAD + j * 4) = o;
}

// ---------------------------------------------------------------------------
extern "C" void kernel_launch(void* const* d_in, const int* in_sizes, int n_in,
                              void* d_out, int out_size, void* d_ws, size_t ws_size,
                              hipStream_t stream)
{
    const float* query  = (const float*)d_in[0];
    const float* value  = (const float*)d_in[1];
    const float* refp   = (const float*)d_in[2];
    const float* W_off  = (const float*)d_in[3];
    const float* b_off  = (const float*)d_in[4];
    const float* W_attn = (const float*)d_in[5];
    const float* b_attn = (const float*)d_in[6];
    const float* W_val  = (const float*)d_in[7];
    const float* b_val  = (const float*)d_in[8];
    const float* W_out  = (const float*)d_in[9];
    const float* b_out  = (const float*)d_in[10];
    float* out = (float*)d_out;

    // workspace layout (bytes), total ~92.5 MB
    char* ws = (char*)d_ws;
    float* offs            = (float*)ws;                           // 20,480,000
    float* logits          = (float*)(ws + 20480000);              // 10,240,000
    unsigned short* vh     = (unsigned short*)(ws + 30720000);     // 20,480,000
    unsigned short* qbf    = (unsigned short*)(ws + 51200000);     // 20,480,000
    unsigned short* vbf    = (unsigned short*)(ws + 71680000);     // 20,480,000
    unsigned short* WT_off  = (unsigned short*)(ws + 92160000);    // 32768 el
    unsigned short* WT_attn = WT_off + 32768;                      // 16384 el
    unsigned short* WT_val  = WT_attn + 16384;                     // 65536 el
    unsigned short* WT_out  = WT_val + 65536;                      // 65536 el
    unsigned short* mid_bf  = qbf;   // alias: qbf dead after logits GEMM

    const dim3 blk(256);
    cast_qv<<<dim3(10000), blk, 0, stream>>>(query, value, qbf, vbf);
    wt_cast<<<dim3(256, 4), blk, 0, stream>>>(W_off, W_attn, W_val, W_out,
                                              WT_off, WT_attn, WT_val, WT_out);
    gemm_bf16<false><<<dim3(2, 625), blk, 0, stream>>>(qbf, WT_off, b_off, offs,
                                                       N_TOK, 128);
    gemm_bf16<false><<<dim3(1, 625), blk, 0, stream>>>(qbf, WT_attn, b_attn, logits,
                                                       N_TOK, 64);
    gemm_bf16<true><<<dim3(4, 625), blk, 0, stream>>>(vbf, WT_val, b_val, vh,
                                                      N_TOK, 256);
    sample_k<<<dim3(N_TOK / 4), blk, 0, stream>>>(vh, offs, logits, refp, mid_bf);
    gemm_bf16<false><<<dim3(4, 625), blk, 0, stream>>>(mid_bf, WT_out, b_out, out,
                                                       N_TOK, 256);
}

// Round 4
// 127.957 us; speedup vs baseline: 2.9876x; 1.2072x over previous
//
#include <hip/hip_runtime.h>
#include <math.h>

#define N_TOK 40000
#define D_MODEL 256
#define NHEAD 8
#define NPOINT 8
#define DHEAD 32
#define HW_DIM 200

typedef __attribute__((ext_vector_type(8))) short short8;
typedef __attribute__((ext_vector_type(4))) float f32x4;
typedef __attribute__((ext_vector_type(8))) unsigned short ushort8v;

__device__ inline unsigned short f2bf(float f) {
    union { float f; unsigned int u; } v; v.f = f;
    unsigned int r = v.u + 0x7FFFu + ((v.u >> 16) & 1u);   // RNE
    return (unsigned short)(r >> 16);
}

__device__ inline float4 bf4f(ushort4 u) {
    float4 r;
    r.x = __uint_as_float((unsigned)u.x << 16);
    r.y = __uint_as_float((unsigned)u.y << 16);
    r.z = __uint_as_float((unsigned)u.z << 16);
    r.w = __uint_as_float((unsigned)u.w << 16);
    return r;
}

// ---------------------------------------------------------------------------
// cast query+value fp32 -> bf16, vectorized 8/thread
// ---------------------------------------------------------------------------
__global__ __launch_bounds__(256)
void cast_qv(const float* __restrict__ q, const float* __restrict__ v,
             unsigned short* __restrict__ qb, unsigned short* __restrict__ vb)
{
    const int PER = (N_TOK * D_MODEL) / 8;          // 1,280,000
    int i = blockIdx.x * 256 + threadIdx.x;
    const float* s; unsigned short* d;
    if (i < PER) { s = q; d = qb; }
    else         { s = v; d = vb; i -= PER; }
    const float4* sp = (const float4*)s;
    float4 x = sp[(size_t)i * 2], y = sp[(size_t)i * 2 + 1];
    ushort8v o;
    o[0] = f2bf(x.x); o[1] = f2bf(x.y); o[2] = f2bf(x.z); o[3] = f2bf(x.w);
    o[4] = f2bf(y.x); o[5] = f2bf(y.y); o[6] = f2bf(y.z); o[7] = f2bf(y.w);
    *(ushort8v*)(d + (size_t)i * 8) = o;
}

// ---------------------------------------------------------------------------
// weight transpose + cast.
// which 0: W_off (N=128) -> rows 0..127 of WTq, bias -> bq[0..127]
// which 1: W_attn (N=64) -> rows 128..191 of WTq, bias -> bq[128..191]
// which 2: W_val -> WT_val,  which 3: W_out -> WT_out
// ---------------------------------------------------------------------------
__global__ __launch_bounds__(256)
void wt_cast(const float* __restrict__ W0, const float* __restrict__ W1,
             const float* __restrict__ W2, const float* __restrict__ W3,
             const float* __restrict__ b0, const float* __restrict__ b1,
             unsigned short* __restrict__ Tq, float* __restrict__ bq,
             unsigned short* __restrict__ T2, unsigned short* __restrict__ T3)
{
    const int which = blockIdx.y;
    const int n = blockIdx.x;
    const int k = threadIdx.x;
    if (which == 0) {
        if (n >= 128) return;
        Tq[(size_t)n * 256 + k] = f2bf(W0[(size_t)k * 128 + n]);
        if (k == 0) bq[n] = b0[n];
    } else if (which == 1) {
        if (n >= 64) return;
        Tq[(size_t)(128 + n) * 256 + k] = f2bf(W1[(size_t)k * 64 + n]);
        if (k == 0) bq[128 + n] = b1[n];
    } else if (which == 2) {
        T2[(size_t)n * 256 + k] = f2bf(W2[(size_t)k * 256 + n]);
    } else {
        T3[(size_t)n * 256 + k] = f2bf(W3[(size_t)k * 256 + n]);
    }
}

// ---------------------------------------------------------------------------
// bf16 MFMA GEMM: C = A[M x 256] @ BT[Nout x 256]^T + bias
// 64x64 tile, 4 waves, 2x2 frags of 16x16x32. global_load_lds width-16,
// XOR k-chunk swizzle on both sides.
// MODE 0: fp32 C[row][col]
// MODE 1: bf16 head-major vh[col>>5][row][col&31]           (value proj)
// MODE 2: fp32 head-major split: col<128 -> offs[8][N][16], else logits[8][N][8]
// ---------------------------------------------------------------------------
template<int MODE>
__global__ __launch_bounds__(256)
void gemm_bf16(const unsigned short* __restrict__ A,
               const unsigned short* __restrict__ BT,
               const float* __restrict__ bias,
               void* __restrict__ Cp, void* __restrict__ Cp2,
               int M, int Nout)
{
    __shared__ short As[64 * 32];
    __shared__ short Bs[64 * 32];

    const int tid  = threadIdx.x;
    const int wid  = tid >> 6;
    const int lane = tid & 63;
    const int m0   = blockIdx.y * 64;
    const int n0   = blockIdx.x * 64;

    const int srow  = tid >> 2;
    const int skc   = tid & 3;
    const int skc_s = skc ^ ((srow >> 1) & 3);
    const unsigned short* gA = A  + (size_t)(m0 + srow) * 256 + skc_s * 8;
    const unsigned short* gB = BT + (size_t)(n0 + srow) * 256 + skc_s * 8;
    auto* ldsA = (__attribute__((address_space(3))) char*)As + wid * 1024;
    auto* ldsB = (__attribute__((address_space(3))) char*)Bs + wid * 1024;

    const int r16 = lane & 15;
    const int g   = lane >> 4;

    f32x4 acc[2][2] = {};

    for (int k0 = 0; k0 < 256; k0 += 32) {
        __syncthreads();
        __builtin_amdgcn_global_load_lds(
            (const __attribute__((address_space(1))) void*)(gA + k0),
            (__attribute__((address_space(3))) void*)ldsA, 16, 0, 0);
        __builtin_amdgcn_global_load_lds(
            (const __attribute__((address_space(1))) void*)(gB + k0),
            (__attribute__((address_space(3))) void*)ldsB, 16, 0, 0);
        __syncthreads();

        short8 a[2], b[2];
        #pragma unroll
        for (int i = 0; i < 2; i++) {
            const int row = (wid >> 1) * 32 + i * 16 + r16;
            const int kra = g ^ ((row >> 1) & 3);
            a[i] = *(const short8*)(As + row * 32 + kra * 8);
            const int col = (wid & 1) * 32 + i * 16 + r16;
            const int krb = g ^ ((col >> 1) & 3);
            b[i] = *(const short8*)(Bs + col * 32 + krb * 8);
        }
        #pragma unroll
        for (int i = 0; i < 2; i++)
            #pragma unroll
            for (int j = 0; j < 2; j++)
                acc[i][j] = __builtin_amdgcn_mfma_f32_16x16x32_bf16(
                    a[i], b[j], acc[i][j], 0, 0, 0);
    }

    const int wr = (wid >> 1) * 32, wc = (wid & 1) * 32;
    #pragma unroll
    for (int j = 0; j < 2; j++) {
        const int col = n0 + wc + j * 16 + r16;
        const float bv = bias[col];
        #pragma unroll
        for (int i = 0; i < 2; i++) {
            #pragma unroll
            for (int r = 0; r < 4; r++) {
                const int row = m0 + wr + i * 16 + g * 4 + r;
                const float o = acc[i][j][r] + bv;
                if (MODE == 1) {
                    const int h = col >> 5, c = col & 31;
                    ((unsigned short*)Cp)[(size_t)h * M * 32 + (size_t)row * 32 + c] = f2bf(o);
                } else if (MODE == 2) {
                    if (col < 128) {
                        const int h = col >> 4, c = col & 15;
                        ((float*)Cp)[((size_t)h * M + row) * 16 + c] = o;
                    } else {
                        const int h = (col - 128) >> 3, c = (col - 128) & 7;
                        ((float*)Cp2)[((size_t)h * M + row) * 8 + c] = o;
                    }
                } else {
                    ((float*)Cp)[(size_t)row * Nout + col] = o;
                }
            }
        }
    }
}

// ---------------------------------------------------------------------------
// Sampling v3: head-split for L2 locality.
// Block = 256 thr handles 32 tokens x 1 head. h = bid & 7 (-> XCD id under
// round-robin dispatch), chunk = bid >> 3 sweeps tokens sequentially per XCD:
// per-head sliding window (~2.2 MB) stays L2-resident.
// Phase 1: lane group (t = tid>>3, p = tid&7): softmax + corner idx/weights.
// Phase 2: (t, quad j = tid&7): gather 4 corners x 8 points, fma into float4.
// ---------------------------------------------------------------------------
__global__ __launch_bounds__(256)
void sample_k(const unsigned short* __restrict__ vh,   // [8][40000][32] bf16
              const float* __restrict__ offs,          // [8][40000][16]
              const float* __restrict__ logits,        // [8][40000][8]
              const float* __restrict__ refp,          // [N][2]
              unsigned short* __restrict__ mid)        // [N][256] bf16
{
    __shared__ int4   s_idx[32][9];   // +1 pad: break 128B-stride banking
    __shared__ float4 s_w[32][9];

    const int bid   = blockIdx.x;
    const int h     = bid & 7;
    const int chunk = bid >> 3;
    const int t     = threadIdx.x >> 3;
    const int pj    = threadIdx.x & 7;
    const int n     = chunk * 32 + t;

    // ---- phase 1: point p = pj ----
    {
        const float rx = refp[2 * n + 0];
        const float ry = refp[2 * n + 1];
        const float l = logits[((size_t)h * N_TOK + n) * 8 + pj];
        float m = l;
        m = fmaxf(m, __shfl_xor(m, 1));
        m = fmaxf(m, __shfl_xor(m, 2));
        m = fmaxf(m, __shfl_xor(m, 4));
        const float e = expf(l - m);
        float s = e;
        s += __shfl_xor(s, 1);
        s += __shfl_xor(s, 2);
        s += __shfl_xor(s, 4);
        const float aw = e * (1.0f / s);

        const float2 o = *(const float2*)(offs + ((size_t)h * N_TOK + n) * 16 + pj * 2);
        float lx = rx + o.x * (1.0f / (float)HW_DIM);
        float ly = ry + o.y * (1.0f / (float)HW_DIM);
        lx = fminf(fmaxf(lx, 0.f), 1.f);
        ly = fminf(fmaxf(ly, 0.f), 1.f);
        const float x = lx * (float)HW_DIM - 0.5f;
        const float y = ly * (float)HW_DIM - 0.5f;
        const float x0f = floorf(x), y0f = floorf(y);
        const float wx = x - x0f, wy = y - y0f;
        const int x0 = (int)x0f, y0 = (int)y0f;
        const int x1 = x0 + 1,   y1 = y0 + 1;
        const float vx0 = (x0 >= 0 && x0 < HW_DIM) ? 1.f : 0.f;
        const float vx1 = (x1 >= 0 && x1 < HW_DIM) ? 1.f : 0.f;
        const float vy0 = (y0 >= 0 && y0 < HW_DIM) ? 1.f : 0.f;
        const float vy1 = (y1 >= 0 && y1 < HW_DIM) ? 1.f : 0.f;
        const int xc0 = min(max(x0, 0), HW_DIM - 1);
        const int xc1 = min(max(x1, 0), HW_DIM - 1);
        const int yc0 = min(max(y0, 0), HW_DIM - 1);
        const int yc1 = min(max(y1, 0), HW_DIM - 1);

        int4 ic;
        ic.x = yc0 * HW_DIM + xc0;
        ic.y = yc0 * HW_DIM + xc1;
        ic.z = yc1 * HW_DIM + xc0;
        ic.w = yc1 * HW_DIM + xc1;
        float4 wc;
        wc.x = (1.f - wx) * (1.f - wy) * aw * vy0 * vx0;
        wc.y = wx * (1.f - wy) * aw * vy0 * vx1;
        wc.z = (1.f - wx) * wy * aw * vy1 * vx0;
        wc.w = wx * wy * aw * vy1 * vx1;

        s_idx[t][pj] = ic;
        s_w[t][pj]   = wc;
    }
    __syncthreads();

    // ---- phase 2: channel quad pj ----
    const char* vb = (const char*)vh;
    const unsigned int hj = (unsigned int)h * (N_TOK * 64u) + (unsigned int)pj * 8u;

    float4 acc = {0.f, 0.f, 0.f, 0.f};
    #pragma unroll
    for (int p = 0; p < NPOINT; p++) {
        const int4   ic = s_idx[t][p];
        const float4 wc = s_w[t][p];
        const float4 v0 = bf4f(*(const ushort4*)(vb + (hj + ((unsigned int)ic.x << 6))));
        const float4 v1 = bf4f(*(const ushort4*)(vb + (hj + ((unsigned int)ic.y << 6))));
        const float4 v2 = bf4f(*(const ushort4*)(vb + (hj + ((unsigned int)ic.z << 6))));
        const float4 v3 = bf4f(*(const ushort4*)(vb + (hj + ((unsigned int)ic.w << 6))));
        acc.x = fmaf(wc.x, v0.x, acc.x); acc.y = fmaf(wc.x, v0.y, acc.y);
        acc.z = fmaf(wc.x, v0.z, acc.z); acc.w = fmaf(wc.x, v0.w, acc.w);
        acc.x = fmaf(wc.y, v1.x, acc.x); acc.y = fmaf(wc.y, v1.y, acc.y);
        acc.z = fmaf(wc.y, v1.z, acc.z); acc.w = fmaf(wc.y, v1.w, acc.w);
        acc.x = fmaf(wc.z, v2.x, acc.x); acc.y = fmaf(wc.z, v2.y, acc.y);
        acc.z = fmaf(wc.z, v2.z, acc.z); acc.w = fmaf(wc.z, v2.w, acc.w);
        acc.x = fmaf(wc.w, v3.x, acc.x); acc.y = fmaf(wc.w, v3.y, acc.y);
        acc.z = fmaf(wc.w, v3.z, acc.z); acc.w = fmaf(wc.w, v3.w, acc.w);
    }
    ushort4 o;
    o.x = f2bf(acc.x); o.y = f2bf(acc.y); o.z = f2bf(acc.z); o.w = f2bf(acc.w);
    *(ushort4*)(mid + (size_t)n * D_MODEL + h * DHEAD + pj * 4) = o;
}

// ---------------------------------------------------------------------------
extern "C" void kernel_launch(void* const* d_in, const int* in_sizes, int n_in,
                              void* d_out, int out_size, void* d_ws, size_t ws_size,
                              hipStream_t stream)
{
    const float* query  = (const float*)d_in[0];
    const float* value  = (const float*)d_in[1];
    const float* refp   = (const float*)d_in[2];
    const float* W_off  = (const float*)d_in[3];
    const float* b_off  = (const float*)d_in[4];
    const float* W_attn = (const float*)d_in[5];
    const float* b_attn = (const float*)d_in[6];
    const float* W_val  = (const float*)d_in[7];
    const float* b_val  = (const float*)d_in[8];
    const float* W_out  = (const float*)d_in[9];
    const float* b_out  = (const float*)d_in[10];
    float* out = (float*)d_out;

    // workspace layout (bytes), total ~92.8 MB
    char* ws = (char*)d_ws;
    float* offs            = (float*)ws;                           // 8*N*16*4 = 20,480,000
    float* logits          = (float*)(ws + 20480000);              // 8*N*8*4  = 10,240,000
    unsigned short* vh     = (unsigned short*)(ws + 30720000);     // 20,480,000
    unsigned short* qbf    = (unsigned short*)(ws + 51200000);     // 20,480,000
    unsigned short* vbf    = (unsigned short*)(ws + 71680000);     // 20,480,000
    unsigned short* WTq    = (unsigned short*)(ws + 92160000);     // 192*256*2 = 98,304
    float*          bq     = (float*)(ws + 92258304);              // 192*4
    unsigned short* WT_val = (unsigned short*)(ws + 92259072);     // 131,072
    unsigned short* WT_out = (unsigned short*)(ws + 92390144);     // 131,072
    unsigned short* mid_bf = qbf;   // alias: qbf dead after q-GEMM

    const dim3 blk(256);
    cast_qv<<<dim3(10000), blk, 0, stream>>>(query, value, qbf, vbf);
    wt_cast<<<dim3(256, 4), blk, 0, stream>>>(W_off, W_attn, W_val, W_out,
                                              b_off, b_attn, WTq, bq, WT_val, WT_out);
    // merged q-GEMM: offsets (cols 0..127) + logits (cols 128..191), head-major
    gemm_bf16<2><<<dim3(3, 625), blk, 0, stream>>>(qbf, WTq, bq, offs, logits,
                                                   N_TOK, 192);
    // value proj -> bf16 head-major vh
    gemm_bf16<1><<<dim3(4, 625), blk, 0, stream>>>(vbf, WT_val, b_val, vh, nullptr,
                                                   N_TOK, 256);
    sample_k<<<dim3((N_TOK / 32) * NHEAD), blk, 0, stream>>>(vh, offs, logits, refp, mid_bf);
    gemm_bf16<0><<<dim3(4, 625), blk, 0, stream>>>(mid_bf, WT_out, b_out, out, nullptr,
                                                   N_TOK, 256);
}

// Round 5
// 122.079 us; speedup vs baseline: 3.1315x; 1.0481x over previous
//
#include <hip/hip_runtime.h>
#include <hip/hip_fp16.h>
#include <math.h>

#define N_TOK 40000
#define D_MODEL 256
#define NHEAD 8
#define NPOINT 8
#define DHEAD 32
#define HW_DIM 200

typedef __attribute__((ext_vector_type(8))) short short8;
typedef __attribute__((ext_vector_type(8))) _Float16 f16x8;
typedef __attribute__((ext_vector_type(4))) float f32x4;
typedef __attribute__((ext_vector_type(8))) unsigned short ushort8v;

__device__ inline unsigned short f2bf(float f) {
    union { float f; unsigned int u; } v; v.f = f;
    unsigned int r = v.u + 0x7FFFu + ((v.u >> 16) & 1u);   // RNE
    return (unsigned short)(r >> 16);
}

__device__ inline __half2 uh2(unsigned int u) {
    union { unsigned int u; __half2 h; } x; x.u = u; return x.h;
}
__device__ inline unsigned int h2u(__half2 h) {
    union { __half2 h; unsigned int u; } x; x.h = h; return x.u;
}

// ---------------------------------------------------------------------------
// weight transpose + cast.
// which 0: W_off (N=128) -> rows 0..127 of WTq (bf16), bias -> bq[0..127]
// which 1: W_attn (N=64) -> rows 128..191 of WTq (bf16), bias -> bq[128..191]
// which 2: W_val -> WT_val (bf16),  which 3: W_out -> WT_out (fp16)
// ---------------------------------------------------------------------------
__global__ __launch_bounds__(256)
void wt_cast(const float* __restrict__ W0, const float* __restrict__ W1,
             const float* __restrict__ W2, const float* __restrict__ W3,
             const float* __restrict__ b0, const float* __restrict__ b1,
             unsigned short* __restrict__ Tq, float* __restrict__ bq,
             unsigned short* __restrict__ T2, unsigned short* __restrict__ T3)
{
    const int which = blockIdx.y;
    const int n = blockIdx.x;
    const int k = threadIdx.x;
    if (which == 0) {
        if (n >= 128) return;
        Tq[(size_t)n * 256 + k] = f2bf(W0[(size_t)k * 128 + n]);
        if (k == 0) bq[n] = b0[n];
    } else if (which == 1) {
        if (n >= 64) return;
        Tq[(size_t)(128 + n) * 256 + k] = f2bf(W1[(size_t)k * 64 + n]);
        if (k == 0) bq[128 + n] = b1[n];
    } else if (which == 2) {
        T2[(size_t)n * 256 + k] = f2bf(W2[(size_t)k * 256 + n]);
    } else {
        T3[(size_t)n * 256 + k] = __half_as_ushort(__float2half(W3[(size_t)k * 256 + n]));
    }
}

// ---------------------------------------------------------------------------
// bf16 MFMA GEMM with fp32 A (fused cast): C = bf16(A[M x 256]) @ BT^T + bias
// A: reg-staged (global fp32 -> RNE bf16 -> swizzled ds_write_b128).
// B: global_load_lds width-16, pre-swizzled source.
// MODE 1: fp16 head-major vh[col>>5][row][col&31]           (value proj)
// MODE 2: fp32 head-major split: col<128 -> offs[8][N][16], else logits[8][N][8]
// ---------------------------------------------------------------------------
template<int MODE>
__global__ __launch_bounds__(256)
void gemm_qv(const float* __restrict__ A,
             const unsigned short* __restrict__ BT,
             const float* __restrict__ bias,
             void* __restrict__ Cp, void* __restrict__ Cp2,
             int M, int Nout)
{
    __shared__ short As[64 * 32];
    __shared__ short Bs[64 * 32];

    const int tid  = threadIdx.x;
    const int wid  = tid >> 6;
    const int lane = tid & 63;
    const int m0   = blockIdx.y * 64;
    const int n0   = blockIdx.x * 64;

    const int srow  = tid >> 2;
    const int skc   = tid & 3;
    const int skc_s = skc ^ ((srow >> 1) & 3);
    const float* gA = A + (size_t)(m0 + srow) * 256 + skc * 8;        // linear k
    const unsigned short* gB = BT + (size_t)(n0 + srow) * 256 + skc_s * 8;
    auto* ldsB = (__attribute__((address_space(3))) char*)Bs + wid * 1024;
    short* wA = As + srow * 32 + skc_s * 8;                           // swizzled dest

    const int r16 = lane & 15;
    const int g   = lane >> 4;

    f32x4 acc[2][2] = {};

    #pragma unroll
    for (int kk = 0; kk < 8; kk++) {
        const int k0 = kk * 32;
        float4 a0 = *(const float4*)(gA + k0);
        float4 a1 = *(const float4*)(gA + k0 + 4);
        __syncthreads();                          // prev iter LDS reads done
        __builtin_amdgcn_global_load_lds(
            (const __attribute__((address_space(1))) void*)(gB + k0),
            (__attribute__((address_space(3))) void*)ldsB, 16, 0, 0);
        short8 ap;
        ap[0] = (short)f2bf(a0.x); ap[1] = (short)f2bf(a0.y);
        ap[2] = (short)f2bf(a0.z); ap[3] = (short)f2bf(a0.w);
        ap[4] = (short)f2bf(a1.x); ap[5] = (short)f2bf(a1.y);
        ap[6] = (short)f2bf(a1.z); ap[7] = (short)f2bf(a1.w);
        *(short8*)wA = ap;
        __syncthreads();                          // drains vm + lgkm

        short8 a[2], b[2];
        #pragma unroll
        for (int i = 0; i < 2; i++) {
            const int row = (wid >> 1) * 32 + i * 16 + r16;
            const int kra = g ^ ((row >> 1) & 3);
            a[i] = *(const short8*)(As + row * 32 + kra * 8);
            const int col = (wid & 1) * 32 + i * 16 + r16;
            const int krb = g ^ ((col >> 1) & 3);
            b[i] = *(const short8*)(Bs + col * 32 + krb * 8);
        }
        #pragma unroll
        for (int i = 0; i < 2; i++)
            #pragma unroll
            for (int j = 0; j < 2; j++)
                acc[i][j] = __builtin_amdgcn_mfma_f32_16x16x32_bf16(
                    a[i], b[j], acc[i][j], 0, 0, 0);
    }

    const int wr = (wid >> 1) * 32, wc = (wid & 1) * 32;
    #pragma unroll
    for (int j = 0; j < 2; j++) {
        const int col = n0 + wc + j * 16 + r16;
        const float bv = bias[col];
        #pragma unroll
        for (int i = 0; i < 2; i++) {
            #pragma unroll
            for (int r = 0; r < 4; r++) {
                const int row = m0 + wr + i * 16 + g * 4 + r;
                const float o = acc[i][j][r] + bv;
                if (MODE == 1) {
                    const int h = col >> 5, c = col & 31;
                    ((unsigned short*)Cp)[(size_t)h * M * 32 + (size_t)row * 32 + c] =
                        __half_as_ushort(__float2half(o));
                } else {
                    if (col < 128) {
                        const int h = col >> 4, c = col & 15;
                        ((float*)Cp)[((size_t)h * M + row) * 16 + c] = o;
                    } else {
                        const int h = (col - 128) >> 3, c = (col - 128) & 7;
                        ((float*)Cp2)[((size_t)h * M + row) * 8 + c] = o;
                    }
                }
            }
        }
    }
}

// ---------------------------------------------------------------------------
// fp16 MFMA GEMM for the output projection: C fp32 = A(fp16) @ BT(fp16)^T + b
// A direct global_load_lds (pre-swizzled source), same structure as gemm_qv.
// ---------------------------------------------------------------------------
__global__ __launch_bounds__(256)
void gemm_out(const unsigned short* __restrict__ A,
              const unsigned short* __restrict__ BT,
              const float* __restrict__ bias,
              float* __restrict__ C, int M, int Nout)
{
    __shared__ short As[64 * 32];
    __shared__ short Bs[64 * 32];

    const int tid  = threadIdx.x;
    const int wid  = tid >> 6;
    const int lane = tid & 63;
    const int m0   = blockIdx.y * 64;
    const int n0   = blockIdx.x * 64;

    const int srow  = tid >> 2;
    const int skc   = tid & 3;
    const int skc_s = skc ^ ((srow >> 1) & 3);
    const unsigned short* gA = A  + (size_t)(m0 + srow) * 256 + skc_s * 8;
    const unsigned short* gB = BT + (size_t)(n0 + srow) * 256 + skc_s * 8;
    auto* ldsA = (__attribute__((address_space(3))) char*)As + wid * 1024;
    auto* ldsB = (__attribute__((address_space(3))) char*)Bs + wid * 1024;

    const int r16 = lane & 15;
    const int g   = lane >> 4;

    f32x4 acc[2][2] = {};

    #pragma unroll
    for (int kk = 0; kk < 8; kk++) {
        const int k0 = kk * 32;
        __syncthreads();
        __builtin_amdgcn_global_load_lds(
            (const __attribute__((address_space(1))) void*)(gA + k0),
            (__attribute__((address_space(3))) void*)ldsA, 16, 0, 0);
        __builtin_amdgcn_global_load_lds(
            (const __attribute__((address_space(1))) void*)(gB + k0),
            (__attribute__((address_space(3))) void*)ldsB, 16, 0, 0);
        __syncthreads();

        f16x8 a[2], b[2];
        #pragma unroll
        for (int i = 0; i < 2; i++) {
            const int row = (wid >> 1) * 32 + i * 16 + r16;
            const int kra = g ^ ((row >> 1) & 3);
            a[i] = *(const f16x8*)(As + row * 32 + kra * 8);
            const int col = (wid & 1) * 32 + i * 16 + r16;
            const int krb = g ^ ((col >> 1) & 3);
            b[i] = *(const f16x8*)(Bs + col * 32 + krb * 8);
        }
        #pragma unroll
        for (int i = 0; i < 2; i++)
            #pragma unroll
            for (int j = 0; j < 2; j++)
                acc[i][j] = __builtin_amdgcn_mfma_f32_16x16x32_f16(
                    a[i], b[j], acc[i][j], 0, 0, 0);
    }

    const int wr = (wid >> 1) * 32, wc = (wid & 1) * 32;
    #pragma unroll
    for (int j = 0; j < 2; j++) {
        const int col = n0 + wc + j * 16 + r16;
        const float bv = bias[col];
        #pragma unroll
        for (int i = 0; i < 2; i++) {
            #pragma unroll
            for (int r = 0; r < 4; r++) {
                const int row = m0 + wr + i * 16 + g * 4 + r;
                C[(size_t)row * Nout + col] = acc[i][j][r] + bv;
            }
        }
    }
}

// ---------------------------------------------------------------------------
// Sampling v4: head-split (h = bid&7 -> XCD pinning), 64 tokens/block.
// Phase 1 (x2 rounds): lane (t, p): softmax + corner idx + half2-packed weights.
// Phase 2: lane (t = tid>>2, c8 = tid&3): 16B fp16 gathers, __hfma2 packed
// accumulate, f32 partial every 2 points. mid written fp16.
// ---------------------------------------------------------------------------
__global__ __launch_bounds__(256)
void sample_k(const unsigned short* __restrict__ vh,   // [8][40000][32] fp16
              const float* __restrict__ offs,          // [8][40000][16]
              const float* __restrict__ logits,        // [8][40000][8]
              const float* __restrict__ refp,          // [N][2]
              unsigned short* __restrict__ mid)        // [N][256] fp16
{
    __shared__ int4  s_idx[64][9];   // +1 pad breaks 128B-stride banking
    __shared__ uint2 s_wp[64][9];

    const int bid   = blockIdx.x;
    const int h     = bid & 7;
    const int chunk = bid >> 3;
    const int n0    = chunk * 64;

    // ---- phase 1 ----
    #pragma unroll
    for (int tt = 0; tt < 2; tt++) {
        const int t  = (threadIdx.x >> 3) + tt * 32;
        const int pj = threadIdx.x & 7;
        const int n  = n0 + t;

        const float rx = refp[2 * n + 0];
        const float ry = refp[2 * n + 1];
        const float l = logits[((size_t)h * N_TOK + n) * 8 + pj];
        float m = l;
        m = fmaxf(m, __shfl_xor(m, 1));
        m = fmaxf(m, __shfl_xor(m, 2));
        m = fmaxf(m, __shfl_xor(m, 4));
        const float e = expf(l - m);
        float s = e;
        s += __shfl_xor(s, 1);
        s += __shfl_xor(s, 2);
        s += __shfl_xor(s, 4);
        const float aw = e * (1.0f / s);

        const float2 o = *(const float2*)(offs + ((size_t)h * N_TOK + n) * 16 + pj * 2);
        float lx = rx + o.x * (1.0f / (float)HW_DIM);
        float ly = ry + o.y * (1.0f / (float)HW_DIM);
        lx = fminf(fmaxf(lx, 0.f), 1.f);
        ly = fminf(fmaxf(ly, 0.f), 1.f);
        const float x = lx * (float)HW_DIM - 0.5f;
        const float y = ly * (float)HW_DIM - 0.5f;
        const float x0f = floorf(x), y0f = floorf(y);
        const float wx = x - x0f, wy = y - y0f;
        const int x0 = (int)x0f, y0 = (int)y0f;
        const int x1 = x0 + 1,   y1 = y0 + 1;
        const float vx0 = (x0 >= 0 && x0 < HW_DIM) ? 1.f : 0.f;
        const float vx1 = (x1 >= 0 && x1 < HW_DIM) ? 1.f : 0.f;
        const float vy0 = (y0 >= 0 && y0 < HW_DIM) ? 1.f : 0.f;
        const float vy1 = (y1 >= 0 && y1 < HW_DIM) ? 1.f : 0.f;
        const int xc0 = min(max(x0, 0), HW_DIM - 1);
        const int xc1 = min(max(x1, 0), HW_DIM - 1);
        const int yc0 = min(max(y0, 0), HW_DIM - 1);
        const int yc1 = min(max(y1, 0), HW_DIM - 1);

        int4 ic;
        ic.x = yc0 * HW_DIM + xc0;
        ic.y = yc0 * HW_DIM + xc1;
        ic.z = yc1 * HW_DIM + xc0;
        ic.w = yc1 * HW_DIM + xc1;
        const float w00 = (1.f - wx) * (1.f - wy) * aw * vy0 * vx0;
        const float w01 = wx * (1.f - wy) * aw * vy0 * vx1;
        const float w10 = (1.f - wx) * wy * aw * vy1 * vx0;
        const float w11 = wx * wy * aw * vy1 * vx1;

        s_idx[t][pj] = ic;
        uint2 pw;
        pw.x = h2u(__floats2half2_rn(w00, w01));
        pw.y = h2u(__floats2half2_rn(w10, w11));
        s_wp[t][pj] = pw;
    }
    __syncthreads();

    // ---- phase 2 ----
    const int t  = threadIdx.x >> 2;     // 0..63 token
    const int c8 = threadIdx.x & 3;      // channel octet
    const int n  = n0 + t;
    const char* vb = (const char*)vh;
    const unsigned int base = (unsigned int)h * (N_TOK * 64u) + (unsigned int)c8 * 16u;

    float accf[8] = {};
    #pragma unroll
    for (int pp = 0; pp < 4; pp++) {
        __half2 ac0 = uh2(0u), ac1 = uh2(0u), ac2 = uh2(0u), ac3 = uh2(0u);
        #pragma unroll
        for (int q = 0; q < 2; q++) {
            const int p = pp * 2 + q;
            const int4  ic = s_idx[t][p];
            const uint2 pw = s_wp[t][p];
            const __half2 w01 = uh2(pw.x), w23 = uh2(pw.y);
            const __half2 wa = __low2half2(w01), wb = __high2half2(w01);
            const __half2 wcc = __low2half2(w23), wd = __high2half2(w23);
            const uint4 qa = *(const uint4*)(vb + (base + ((unsigned int)ic.x << 6)));
            const uint4 qb = *(const uint4*)(vb + (base + ((unsigned int)ic.y << 6)));
            const uint4 qc = *(const uint4*)(vb + (base + ((unsigned int)ic.z << 6)));
            const uint4 qd = *(const uint4*)(vb + (base + ((unsigned int)ic.w << 6)));
            ac0 = __hfma2(wa, uh2(qa.x), ac0); ac1 = __hfma2(wa, uh2(qa.y), ac1);
            ac2 = __hfma2(wa, uh2(qa.z), ac2); ac3 = __hfma2(wa, uh2(qa.w), ac3);
            ac0 = __hfma2(wb, uh2(qb.x), ac0); ac1 = __hfma2(wb, uh2(qb.y), ac1);
            ac2 = __hfma2(wb, uh2(qb.z), ac2); ac3 = __hfma2(wb, uh2(qb.w), ac3);
            ac0 = __hfma2(wcc, uh2(qc.x), ac0); ac1 = __hfma2(wcc, uh2(qc.y), ac1);
            ac2 = __hfma2(wcc, uh2(qc.z), ac2); ac3 = __hfma2(wcc, uh2(qc.w), ac3);
            ac0 = __hfma2(wd, uh2(qd.x), ac0); ac1 = __hfma2(wd, uh2(qd.y), ac1);
            ac2 = __hfma2(wd, uh2(qd.z), ac2); ac3 = __hfma2(wd, uh2(qd.w), ac3);
        }
        float2 f;
        f = __half22float2(ac0); accf[0] += f.x; accf[1] += f.y;
        f = __half22float2(ac1); accf[2] += f.x; accf[3] += f.y;
        f = __half22float2(ac2); accf[4] += f.x; accf[5] += f.y;
        f = __half22float2(ac3); accf[6] += f.x; accf[7] += f.y;
    }

    ushort8v o;
    #pragma unroll
    for (int k = 0; k < 8; k++) o[k] = __half_as_ushort(__float2half(accf[k]));
    *(ushort8v*)(mid + (size_t)n * D_MODEL + h * DHEAD + c8 * 8) = o;
}

// ---------------------------------------------------------------------------
extern "C" void kernel_launch(void* const* d_in, const int* in_sizes, int n_in,
                              void* d_out, int out_size, void* d_ws, size_t ws_size,
                              hipStream_t stream)
{
    const float* query  = (const float*)d_in[0];
    const float* value  = (const float*)d_in[1];
    const float* refp   = (const float*)d_in[2];
    const float* W_off  = (const float*)d_in[3];
    const float* b_off  = (const float*)d_in[4];
    const float* W_attn = (const float*)d_in[5];
    const float* b_attn = (const float*)d_in[6];
    const float* W_val  = (const float*)d_in[7];
    const float* b_val  = (const float*)d_in[8];
    const float* W_out  = (const float*)d_in[9];
    const float* b_out  = (const float*)d_in[10];
    float* out = (float*)d_out;

    // workspace layout (bytes), total ~72 MB
    char* ws = (char*)d_ws;
    float* offs            = (float*)ws;                           // 20,480,000
    float* logits          = (float*)(ws + 20480000);              // 10,240,000
    unsigned short* vh     = (unsigned short*)(ws + 30720000);     // fp16, 20,480,000
    unsigned short* mid    = (unsigned short*)(ws + 51200000);     // fp16, 20,480,000
    unsigned short* WTq    = (unsigned short*)(ws + 71680000);     // 98,304
    float*          bq     = (float*)(ws + 71778304);              // 768
    unsigned short* WT_val = (unsigned short*)(ws + 71779072);     // 131,072
    unsigned short* WT_out = (unsigned short*)(ws + 71910144);     // 131,072

    const dim3 blk(256);
    wt_cast<<<dim3(256, 4), blk, 0, stream>>>(W_off, W_attn, W_val, W_out,
                                              b_off, b_attn, WTq, bq, WT_val, WT_out);
    // merged q-GEMM: offsets (cols 0..127) + logits (cols 128..191), head-major
    gemm_qv<2><<<dim3(3, 625), blk, 0, stream>>>(query, WTq, bq, offs, logits,
                                                 N_TOK, 192);
    // value proj -> fp16 head-major vh
    gemm_qv<1><<<dim3(4, 625), blk, 0, stream>>>(value, WT_val, b_val, vh, nullptr,
                                                 N_TOK, 256);
    sample_k<<<dim3((N_TOK / 64) * NHEAD), blk, 0, stream>>>(vh, offs, logits, refp, mid);
    gemm_out<<<dim3(4, 625), blk, 0, stream>>>(mid, WT_out, b_out, out, N_TOK, 256);
}